// Round 7
// baseline (3013.430 us; speedup 1.0000x reference)
//
#include <hip/hip_runtime.h>

typedef __bf16 bf16x8 __attribute__((ext_vector_type(8)));
typedef float f32x4 __attribute__((ext_vector_type(4)));
typedef unsigned int u32x4 __attribute__((ext_vector_type(4)));

#define S_LEN 256
#define BATCH 64
#define HID   1024
#define NWG   256
#define SBH   (S_LEN * BATCH * HID)   /* 16777216 */
#define BH    (BATCH * HID)           /* 65536 */

__device__ __forceinline__ float sigm(float v) { return 1.0f / (1.0f + __expf(-v)); }
__device__ __forceinline__ float tanh_fast(float v) {
  float e = __expf(-2.0f * __builtin_fabsf(v));
  float r = (1.0f - e) / (1.0f + e);
  return __builtin_copysignf(r, v);
}

// Pack 8 f32 -> 8 bf16 (RNE via compiler cvt) into one 16B word.
__device__ __forceinline__ u32x4 cvt8(float4 a, float4 b) {
  union { unsigned short us[8]; u32x4 v; } r;
  r.us[0] = __builtin_bit_cast(unsigned short, (__bf16)a.x);
  r.us[1] = __builtin_bit_cast(unsigned short, (__bf16)a.y);
  r.us[2] = __builtin_bit_cast(unsigned short, (__bf16)a.z);
  r.us[3] = __builtin_bit_cast(unsigned short, (__bf16)a.w);
  r.us[4] = __builtin_bit_cast(unsigned short, (__bf16)b.x);
  r.us[5] = __builtin_bit_cast(unsigned short, (__bf16)b.y);
  r.us[6] = __builtin_bit_cast(unsigned short, (__bf16)b.z);
  r.us[7] = __builtin_bit_cast(unsigned short, (__bf16)b.w);
  return r.v;
}

// 8 x global_load_dwordx4 + internal vmcnt(0), ONE asm block (proven pattern:
// no in-flight registers are ever visible to the register allocator).
#define LOAD8_X4(dst, base, MODS)                                             \
  asm volatile(                                                               \
      "global_load_dwordx4 %0, %8, off offset:0 " MODS "\n\t"                 \
      "global_load_dwordx4 %1, %8, off offset:64 " MODS "\n\t"                \
      "global_load_dwordx4 %2, %8, off offset:128 " MODS "\n\t"               \
      "global_load_dwordx4 %3, %8, off offset:192 " MODS "\n\t"               \
      "global_load_dwordx4 %4, %8, off offset:256 " MODS "\n\t"               \
      "global_load_dwordx4 %5, %8, off offset:320 " MODS "\n\t"               \
      "global_load_dwordx4 %6, %8, off offset:384 " MODS "\n\t"               \
      "global_load_dwordx4 %7, %8, off offset:448 " MODS "\n\t"               \
      "s_waitcnt vmcnt(0)"                                                    \
      : "=&v"((dst)[0]), "=&v"((dst)[1]), "=&v"((dst)[2]), "=&v"((dst)[3]),   \
        "=&v"((dst)[4]), "=&v"((dst)[5]), "=&v"((dst)[6]), "=&v"((dst)[7])    \
      : "v"(base)                                                             \
      : "memory")

#define CHECK8(H, MEXP, BAD)                                                  \
  do {                                                                        \
    BAD = 0;                                                                  \
    _Pragma("unroll")                                                         \
    for (int _kc = 0; _kc < 8; ++_kc) {                                       \
      u32x4 _w = (H)[_kc];                                                    \
      BAD |= ((_w[0] ^ (MEXP)) & 0x00010001u);                                \
      BAD |= ((_w[1] ^ (MEXP)) & 0x00010001u);                                \
      BAD |= ((_w[2] ^ (MEXP)) & 0x00010001u);                                \
      BAD |= ((_w[3] ^ (MEXP)) & 0x00010001u);                                \
    }                                                                         \
  } while (0)

#define HMFMA(H)                                                              \
  do {                                                                        \
    _Pragma("unroll")                                                         \
    for (int _kc = 0; _kc < 8; ++_kc) {                                       \
      bf16x8 _a = __builtin_bit_cast(bf16x8, (H)[_kc]);                       \
      acc0 = __builtin_amdgcn_mfma_f32_16x16x32_bf16(_a, __builtin_bit_cast(bf16x8, Braw[ 0 + _kc]), acc0, 0, 0, 0); \
      acc1 = __builtin_amdgcn_mfma_f32_16x16x32_bf16(_a, __builtin_bit_cast(bf16x8, Braw[ 8 + _kc]), acc1, 0, 0, 0); \
      acc2 = __builtin_amdgcn_mfma_f32_16x16x32_bf16(_a, __builtin_bit_cast(bf16x8, Braw[16 + _kc]), acc2, 0, 0, 0); \
      acc3 = __builtin_amdgcn_mfma_f32_16x16x32_bf16(_a, __builtin_bit_cast(bf16x8, Braw[24 + _kc]), acc3, 0, 0, 0); \
    }                                                                         \
  } while (0)

// Early issue of a 16B frag-pair as two 8B AGENT-scope atomic loads.
// Compiler-managed destinations: regalloc inserts its own waitcnt before any
// copy/spill/use — structurally safe in-flight state (unlike asm outputs).
#define EARLY_LOAD16(EARR, HB)                                                \
  do {                                                                        \
    _Pragma("unroll")                                                         \
    for (int _kc = 0; _kc < 8; ++_kc) {                                       \
      (EARR)[2 * _kc] = __hip_atomic_load(                                    \
          (const unsigned long long*)((HB) + _kc * 32),                       \
          __ATOMIC_RELAXED, __HIP_MEMORY_SCOPE_AGENT);                        \
      (EARR)[2 * _kc + 1] = __hip_atomic_load(                                \
          (const unsigned long long*)((HB) + _kc * 32 + 4),                   \
          __ATOMIC_RELAXED, __HIP_MEMORY_SCOPE_AGENT);                        \
    }                                                                         \
  } while (0)

// Prep: weights layout-convert to bf16 + h0 seed + region-1 poison.
// (x consumed as f32 directly by lstm_kernel — no 32MB x conversion pass.)
__global__ void prep_kernel(const float* __restrict__ h0,
                            const float* __restrict__ Wf, const float* __restrict__ Wi,
                            const float* __restrict__ Wg, const float* __restrict__ Wo,
                            __bf16* __restrict__ w_x, __bf16* __restrict__ w_h,
                            __bf16* __restrict__ h_buf) {
  size_t tid = (size_t)blockIdx.x * blockDim.x + threadIdx.x;
  size_t stride = (size_t)gridDim.x * blockDim.x;

#define W_CONV(W, gidx)                                                        \
  for (size_t i = tid; i < (size_t)(1024 * 128); i += stride) {                \
    int j   = (int)(i >> 7);                                                   \
    int kc8 = (int)(i & 127);                                                  \
    const float* row = (W) + (size_t)j * 2048;                                 \
    const float4* sx = (const float4*)(row + kc8 * 8);                         \
    const float4* sh = (const float4*)(row + 1024 + kc8 * 8);                  \
    size_t dst = (size_t)((gidx) * 1024 + j) * 128 + kc8;                      \
    ((u32x4*)w_x)[dst] = cvt8(sx[0], sx[1]);                                   \
    ((u32x4*)w_h)[dst] = cvt8(sh[0], sh[1]);                                   \
  }
  W_CONV(Wf, 0)
  W_CONV(Wi, 1)
  W_CONV(Wg, 2)
  W_CONV(Wo, 3)
#undef W_CONV

  // h0 -> bf16, bit0 cleared (epoch marker 0 for consume-step 0)
  for (size_t i = tid; i < (size_t)(BH / 8); i += stride) {
    const float4* s = (const float4*)h0 + i * 2;
    u32x4 v = cvt8(s[0], s[1]);
    v &= 0xFFFEFFFEu;
    ((u32x4*)h_buf)[i] = v;
  }

  // region 1 poison: bit0=1 everywhere (stale vs first producer marker 0)
  for (size_t i = tid; i < (size_t)(BH / 8); i += stride) {
    u32x4 p = {0x00010001u, 0x00010001u, 0x00010001u, 0x00010001u};
    ((u32x4*)(h_buf + BH))[i] = p;
  }
}

// v7 = v4's proven flag-free epoch-marker protocol (957us) +
//  - early issue of next step's h via 16 compiler-managed AGENT atomic ull
//    loads (flight overlaps publish visibility + window work); loop top checks
//    markers on the landed values; stale => proven single-asm-block full-reload
//    retry (guaranteed progress, no in-flight asm registers anywhere).
//  - x consumed as f32 with in-register cvt (kills the 32MB prep pass).
//  - zbuf XOR swizzle: write AND read exactly 2-way bank aliased (free).
__global__ __launch_bounds__(256, 1) void lstm_kernel(
    const float* __restrict__ x, const float* __restrict__ c0,
    const float* __restrict__ bfp, const float* __restrict__ bip,
    const float* __restrict__ bgp, const float* __restrict__ bop,
    const __bf16* __restrict__ w_x, const __bf16* __restrict__ w_h,
    __bf16* __restrict__ h_buf, float* __restrict__ out) {
  const int tid    = threadIdx.x;
  const int wgid   = blockIdx.x;
  const int m_idx  = wgid & 3;
  const int m_base = m_idx * 16;
  const int U      = (wgid >> 2) * 16;
  const int wave   = tid >> 6;
  const int lane   = tid & 63;
  const int l16    = lane & 15;
  const int kq8    = (lane >> 4) * 8;
  const int kbase  = wave * 256;

  __shared__ float zbuf[2][4][16][64];       // XOR-swizzled, no pad
  __shared__ unsigned short hpack[16][16];

  // ---- Resident B: 64 frags. [0..31] = Wh (4 gates x 8 kc), [32..63] = Wx ----
  u32x4 Braw[64];
#pragma unroll
  for (int n = 0; n < 4; ++n) {
    unsigned long gbh =
        (unsigned long)(w_h + (size_t)(n * 1024 + U + l16) * HID + kbase + kq8);
    LOAD8_X4(&Braw[n * 8], gbh, "");
  }
#pragma unroll
  for (int n = 0; n < 4; ++n) {
    unsigned long gbx =
        (unsigned long)(w_x + (size_t)(n * 1024 + U + l16) * HID + kbase + kq8);
    LOAD8_X4(&Braw[32 + n * 8], gbx, "");
  }

  const int b_loc  = tid >> 4;
  const int u_loc  = tid & 15;
  const int j_t    = U + u_loc;
  const int b_glob = m_base + b_loc;
  float c = c0[(size_t)b_glob * HID + j_t];
  const float bias_f = bfp[j_t], bias_i = bip[j_t], bias_g = bgp[j_t], bias_o = bop[j_t];

  // ---- Prologue: x(0) partials from f32; x(1) staged; h(0) early-issued ----
  u32x4 Araw_x[8];
  {
    const float* xp = x + (size_t)(m_base + l16) * HID + kbase + kq8;
#pragma unroll
    for (int kc = 0; kc < 8; ++kc) {
      float4 lo = *(const float4*)(xp + kc * 32);
      float4 hi = *(const float4*)(xp + kc * 32 + 4);
      Araw_x[kc] = cvt8(lo, hi);
    }
  }
  f32x4 accx0 = {0,0,0,0}, accx1 = {0,0,0,0}, accx2 = {0,0,0,0}, accx3 = {0,0,0,0};
#pragma unroll
  for (int kc = 0; kc < 8; ++kc) {
    bf16x8 a = __builtin_bit_cast(bf16x8, Araw_x[kc]);
    accx0 = __builtin_amdgcn_mfma_f32_16x16x32_bf16(a, __builtin_bit_cast(bf16x8, Braw[32 +  0 + kc]), accx0, 0, 0, 0);
    accx1 = __builtin_amdgcn_mfma_f32_16x16x32_bf16(a, __builtin_bit_cast(bf16x8, Braw[32 +  8 + kc]), accx1, 0, 0, 0);
    accx2 = __builtin_amdgcn_mfma_f32_16x16x32_bf16(a, __builtin_bit_cast(bf16x8, Braw[32 + 16 + kc]), accx2, 0, 0, 0);
    accx3 = __builtin_amdgcn_mfma_f32_16x16x32_bf16(a, __builtin_bit_cast(bf16x8, Braw[32 + 24 + kc]), accx3, 0, 0, 0);
  }
  {
    const float* xp = x + ((size_t)BATCH + m_base + l16) * HID + kbase + kq8;
#pragma unroll
    for (int kc = 0; kc < 8; ++kc) {
      float4 lo = *(const float4*)(xp + kc * 32);
      float4 hi = *(const float4*)(xp + kc * 32 + 4);
      Araw_x[kc] = cvt8(lo, hi);
    }
  }

  const __bf16* hb_base = h_buf + (size_t)(m_base + l16) * HID + kbase + kq8;
  const unsigned long ga_base = (unsigned long)hb_base;

  unsigned long long e[16];
  EARLY_LOAD16(e, hb_base);              // region 0 holds fresh h0 (marker 0)

  for (int t = 0; t < S_LEN; ++t) {
    const size_t roff = (t & 1) ? (size_t)BH : 0;
    const unsigned mexp = ((unsigned)(t >> 1) & 1u) * 0x00010001u;
    const unsigned long ga = ga_base + roff * 2;   // bf16 -> bytes
    const int zp = t & 1;

    // ---- Accept h: check early-landed values; stale => full-reload retry ----
    f32x4 acc0 = accx0, acc1 = accx1, acc2 = accx2, acc3 = accx3;
    {
      u32x4 Ah[8];
#pragma unroll
      for (int kc = 0; kc < 8; ++kc) {
        unsigned long long lo = e[2 * kc], hi = e[2 * kc + 1];
        Ah[kc] = (u32x4){(unsigned)lo, (unsigned)(lo >> 32),
                         (unsigned)hi, (unsigned)(hi >> 32)};
      }
      unsigned bad;
      CHECK8(Ah, mexp, bad);
      if (__builtin_expect(__ballot(bad != 0) != 0ull, 0)) {
        do {
          __builtin_amdgcn_s_sleep(1);
          LOAD8_X4(Ah, ga, "sc0 sc1");
          CHECK8(Ah, mexp, bad);
        } while (__ballot(bad != 0) != 0ull);
      }
      HMFMA(Ah);
    }

    // ---- z partials to LDS (XOR-swizzled: 2-way banks on write & read) ----
    {
      int q = lane >> 4;
#pragma unroll
      for (int r = 0; r < 4; ++r) {
        int row = q * 4 + r;
        int s = ((row ^ (row >> 2)) & 3) << 4;
        zbuf[zp][wave][row][( 0 + l16) ^ s] = acc0[r];
        zbuf[zp][wave][row][(16 + l16) ^ s] = acc1[r];
        zbuf[zp][wave][row][(32 + l16) ^ s] = acc2[r];
        zbuf[zp][wave][row][(48 + l16) ^ s] = acc3[r];
      }
    }
    __syncthreads();   // the only intra-WG barrier per step

    // ---- Combine gates, update c, h ----
    float h;
    {
      const int row = b_loc;
      const int s = ((row ^ (row >> 2)) & 3) << 4;
      float zf = 0.f, zi = 0.f, zg = 0.f, zo = 0.f;
#pragma unroll
      for (int w = 0; w < 4; ++w) {
        zf += zbuf[zp][w][row][( 0 + u_loc) ^ s];
        zi += zbuf[zp][w][row][(16 + u_loc) ^ s];
        zg += zbuf[zp][w][row][(32 + u_loc) ^ s];
        zo += zbuf[zp][w][row][(48 + u_loc) ^ s];
      }
      float fg = sigm(zf + bias_f);
      float ig = sigm(zi + bias_i);
      float gg = tanh_fast(zg + bias_g);
      float og = sigm(zo + bias_o);
      c = fg * c + ig * gg;
      h = og * tanh_fast(c);
    }

    if (t < S_LEN - 1) {
      const size_t woff = (t & 1) ? 0 : (size_t)BH;

      // ---- Publish h with next epoch marker (per-wave, fire-and-forget) ----
      {
        unsigned short hbv = __builtin_bit_cast(unsigned short, (__bf16)h);
        hbv = (unsigned short)((hbv & 0xFFFEu) | (unsigned)(((t + 1) >> 1) & 1));
        hpack[b_loc][u_loc] = hbv;
      }
      asm volatile("s_waitcnt lgkmcnt(0)" ::: "memory");
      __builtin_amdgcn_sched_barrier(0);
      if (lane < 8) {
        int b = 4 * wave + (lane >> 1), half = lane & 1;
        u32x4 hv = *(const u32x4*)(&hpack[b][half * 8]);
        unsigned long ha = (unsigned long)(h_buf + woff +
                                           (size_t)(m_base + b) * HID + U + half * 8);
        asm volatile("global_store_dwordx4 %0, %1, off sc0 sc1"
                     :: "v"(ha), "v"(hv) : "memory");
      }

      // ---- Early issue for t+1 (compiler-managed; flight spans the window) ----
      EARLY_LOAD16(e, hb_base + woff);

      // ---- Window: out-write + x-side MFMA for t+1 + x(t+2) prefetch (f32) ----
      {
        size_t oi = ((size_t)(t * BATCH + b_glob)) * HID + j_t;
        out[oi] = x[oi] + h;
      }
      accx0 = (f32x4){0,0,0,0}; accx1 = (f32x4){0,0,0,0};
      accx2 = (f32x4){0,0,0,0}; accx3 = (f32x4){0,0,0,0};
#pragma unroll
      for (int kc = 0; kc < 8; ++kc) {
        bf16x8 a = __builtin_bit_cast(bf16x8, Araw_x[kc]);
        accx0 = __builtin_amdgcn_mfma_f32_16x16x32_bf16(a, __builtin_bit_cast(bf16x8, Braw[32 +  0 + kc]), accx0, 0, 0, 0);
        accx1 = __builtin_amdgcn_mfma_f32_16x16x32_bf16(a, __builtin_bit_cast(bf16x8, Braw[32 +  8 + kc]), accx1, 0, 0, 0);
        accx2 = __builtin_amdgcn_mfma_f32_16x16x32_bf16(a, __builtin_bit_cast(bf16x8, Braw[32 + 16 + kc]), accx2, 0, 0, 0);
        accx3 = __builtin_amdgcn_mfma_f32_16x16x32_bf16(a, __builtin_bit_cast(bf16x8, Braw[32 + 24 + kc]), accx3, 0, 0, 0);
      }
      {
        int tn = (t + 2 < S_LEN) ? (t + 2) : (S_LEN - 1);
        const float* xp = x + ((size_t)(tn * BATCH + m_base + l16)) * HID + kbase + kq8;
#pragma unroll
        for (int kc = 0; kc < 8; ++kc) {
          float4 lo = *(const float4*)(xp + kc * 32);
          float4 hi = *(const float4*)(xp + kc * 32 + 4);
          Araw_x[kc] = cvt8(lo, hi);
        }
      }
    } else {
      size_t oi = ((size_t)(t * BATCH + b_glob)) * HID + j_t;
      out[oi] = x[oi] + h;
      out[(size_t)SBH + (size_t)b_glob * HID + j_t] = h;         // h_f
      out[(size_t)SBH + BH + (size_t)b_glob * HID + j_t] = c;    // c_f
    }
  }
}

extern "C" void kernel_launch(void* const* d_in, const int* in_sizes, int n_in,
                              void* d_out, int out_size, void* d_ws, size_t ws_size,
                              hipStream_t stream) {
  const float* x   = (const float*)d_in[0];
  const float* h0  = (const float*)d_in[1];
  const float* c0  = (const float*)d_in[2];
  const float* Wf  = (const float*)d_in[3];
  const float* bf_ = (const float*)d_in[4];
  const float* Wi  = (const float*)d_in[5];
  const float* bi_ = (const float*)d_in[6];
  const float* Wg  = (const float*)d_in[7];
  const float* bg_ = (const float*)d_in[8];
  const float* Wo  = (const float*)d_in[9];
  const float* bo_ = (const float*)d_in[10];

  char* ws = (char*)d_ws;
  size_t off = 0;
  __bf16* w_x  = (__bf16*)(ws + off); off += (size_t)4 * 1024 * 1024 * 2;  // 8 MB
  __bf16* w_h  = (__bf16*)(ws + off); off += (size_t)4 * 1024 * 1024 * 2;  // 8 MB
  __bf16* h_buf = (__bf16*)(ws + off); off += (size_t)2 * BH * 2;          // 256 KB
  if (ws_size < off) return;

  float* out = (float*)d_out;

  prep_kernel<<<2048, 256, 0, stream>>>(h0, Wf, Wi, Wg, Wo, w_x, w_h, h_buf);
  lstm_kernel<<<NWG, 256, 0, stream>>>(x, c0, bf_, bi_, bg_, bo_, w_x, w_h, h_buf, out);
}